// Round 17
// baseline (171.051 us; speedup 1.0000x reference)
//
#include <hip/hip_runtime.h>
#include <hip/hip_bf16.h>

#define DEV static __device__ __forceinline__

typedef unsigned short u16;
typedef unsigned int u32;
typedef __attribute__((ext_vector_type(8))) short short8;
typedef __attribute__((ext_vector_type(4))) float f32x4;
typedef __attribute__((ext_vector_type(16))) float f32x16;
typedef __attribute__((ext_vector_type(4))) u32 u32x4;

static constexpr int Bsz = 4, Ssz = 2048, Dsz = 1024, Hn = 16, HD = 64;
static constexpr int Mrows = Bsz * Ssz;  // 8192

DEV u16 f2bu(float f) {
  union { float f; u32 u; } a; a.f = f;
  u32 u = a.u;
  u32 r = (u + 0x7FFFu + ((u >> 16) & 1u)) >> 16;
  return (u16)r;
}
DEV float b2f(u16 v) {
  union { u32 u; float f; } a; a.u = ((u32)v) << 16;
  return a.f;
}
DEV u32 pk2(float lo, float hi2) {  // packed bf16 pair (RNE), lo -> [15:0]
  __hip_bfloat162 t = __float22bfloat162_rn(make_float2(lo, hi2));
  u32 r; __builtin_memcpy(&r, &t, 4); return r;
}
DEV f32x16 mfma3232(short8 a, short8 b, f32x16 c) {
  return __builtin_amdgcn_mfma_f32_32x32x16_bf16(a, b, c, 0, 0, 0);
}
DEV f32x4 mfma16(short8 a, short8 b, f32x4 c) {
  return __builtin_amdgcn_mfma_f32_16x16x32_bf16(a, b, c, 0, 0, 0);
}
DEV float ex2(float x) { return __builtin_amdgcn_exp2f(x); }

// ------ prep: fp32->bf16 casts (x, w_qkv, w_out) + RoPE cos/sin table -------
__global__ void k_prep(const float4* __restrict__ s0, ushort4* __restrict__ d0, int n0,
                       const float4* __restrict__ s1, ushort4* __restrict__ d1, int n1,
                       const float4* __restrict__ s2, ushort4* __restrict__ d2, int n2,
                       float2* __restrict__ cst) {
  const int stride = gridDim.x * blockDim.x;
  const int ncast = n0 + n1 + n2;
  const int total = ncast + Ssz * 32;
  for (int i = blockIdx.x * blockDim.x + threadIdx.x; i < total; i += stride) {
    if (i < ncast) {
      const float4* s; ushort4* d; int k;
      if (i < n0) { s = s0; d = d0; k = i; }
      else if (i < n0 + n1) { s = s1; d = d1; k = i - n0; }
      else { s = s2; d = d2; k = i - n0 - n1; }
      float4 v = s[k];
      ushort4 o;
      o.x = f2bu(v.x); o.y = f2bu(v.y); o.z = f2bu(v.z); o.w = f2bu(v.w);
      d[k] = o;
    } else {
      const int k = i - ncast;
      const int s = k >> 5, dd = k & 31;
      const float inv = powf(10000.0f, -(float)dd / 32.0f);
      const float fr = (float)s * inv;
      cst[k] = make_float2(cosf(fr), sinf(fr));
    }
  }
}

DEV void cp16(const u16* g, u16* l) {
  __builtin_amdgcn_global_load_lds((const __attribute__((address_space(1))) u32*)g,
                                   (__attribute__((address_space(3))) u32*)l, 16, 0, 0);
}

// ---------------- GEMM (8-phase-style, 256x128 tile): C = A * W^T -----------
// 512 threads = 8 waves (4M x 2N), wave output 64x64, acc[4][4] f32x4.
// LDS: 3 rotating buffers at K-step 64: A = 3 x 2half x [128][64], B = 3 x
// [128][64] u16 (144 KB). oct^(row&7) swizzle (R9-proven, 0 bank conflicts),
// linear global_load_lds dest + pre-swizzled source.
// Per K-tile group: s_waitcnt vmcnt(6) [prev group's 3 staged units stay in
// flight — T4 counted, never drain-0 until the last group] + s_barrier; then
// 4 phases: {stage one 16KB unit of kt+2 || ds_read frags -> raw s_barrier ->
// setprio(1) 8 MFMA setprio(0) -> raw s_barrier}. Unit of kt+2 overwrites
// buffer (kt+2)%3 whose last reads (kt-1) completed before this group's
// entry barrier. Cross-wave stage visibility = own vmcnt + shared barrier.
// Epilogues LDS-coalesced: q/k thirds RoPE-fused; v third transposed into vt;
// f32 (out-proj) in two row-half passes.
template <bool OUTBF16>
__global__ __launch_bounds__(512, 2) void k_gemm2(const u16* __restrict__ A,
                                                  const u16* __restrict__ W,
                                                  void* __restrict__ C, int N, int K,
                                                  const float2* __restrict__ cst, int cpx,
                                                  u16* __restrict__ vtp) {
  __shared__ __align__(16) u16 SMEM[73728];  // 144 KB
  const int tid = threadIdx.x;
  const int wid = tid >> 6, lane = tid & 63;
  const int lr = lane & 15, u = lane >> 4;
  const int x7 = lane & 7;
  const int wm = wid >> 1, wn = wid & 1;  // wave rows wm*64.., cols wn*64..

  const int wg = blockIdx.x;
  const int xcd = wg & 7;
  const int jj = wg >> 3;
  const int brow = (jj / cpx) * 256;
  const int bcol = (xcd * cpx + jj % cpx) * 128;

  // staging map: thread covers rows (tid>>3) and (tid>>3)+64 of a 128-row
  // unit; source octet pre-swizzled (constant across rounds since +64 ≡ 0 mod 8)
  const int rw = tid >> 3;
  const int octS = ((tid & 7) ^ (rw & 7)) * 8;
  const u16* aS0 = A + (size_t)(brow + rw) * K + octS;        // A half0
  const u16* aS1 = A + (size_t)(brow + 128 + rw) * K + octS;  // A half1
  const u16* bS  = W + (size_t)(bcol + rw) * K + octS;
  const int dOff = tid * 8;

#define STGU(ps, pd, ko)                          \
  do {                                            \
    cp16((ps) + (ko), (pd));                      \
    cp16((ps) + (size_t)64 * K + (ko), (pd) + 4096); \
  } while (0)

  const int arow = (wm & 1) * 64 + lr;      // + mr*16 : row within A half
  const u16* AhB = SMEM + (wm >> 1) * 8192; // wave's A half base (+ buf*16384)
  const int brih = wn * 64 + lr;            // + nc*16 : row within B tile

  f32x4 acc[4][4];
#pragma unroll
  for (int i = 0; i < 4; ++i)
#pragma unroll
    for (int j2 = 0; j2 < 4; ++j2) acc[i][j2] = (f32x4){0.f, 0.f, 0.f, 0.f};

  const int KT = K >> 6;  // 16

  // prologue: kt0 -> buf0, kt1 -> buf1 (unit order A-h0, A-h1, B)
  STGU(aS0, SMEM + dOff, 0);
  STGU(aS1, SMEM + 8192 + dOff, 0);
  STGU(bS, SMEM + 49152 + dOff, 0);
  STGU(aS0, SMEM + 16384 + dOff, 64);
  STGU(aS1, SMEM + 24576 + dOff, 64);
  STGU(bS, SMEM + 57344 + dOff, 64);

#define PHASE(nc)                                                     \
  {                                                                   \
    const u16* br = Bb + (brih + (nc) * 16) * 64;                     \
    short8 b0 = *(const short8*)(br + (u ^ x7) * 8);                  \
    short8 b1 = *(const short8*)(br + ((4 + u) ^ x7) * 8);            \
    asm volatile("s_barrier" ::: "memory");                           \
    __builtin_amdgcn_s_setprio(1);                                    \
    _Pragma("unroll") for (int mr = 0; mr < 4; ++mr) {                \
      acc[mr][(nc)] = mfma16(af0[mr], b0, acc[mr][(nc)]);             \
      acc[mr][(nc)] = mfma16(af1[mr], b1, acc[mr][(nc)]);             \
    }                                                                 \
    __builtin_amdgcn_s_setprio(0);                                    \
    asm volatile("s_barrier" ::: "memory");                           \
  }

  int buf = 0, sbuf = 2;
  for (int kt = 0; kt < KT; ++kt) {
    if (kt + 1 < KT) asm volatile("s_waitcnt vmcnt(6)" ::: "memory");
    else             asm volatile("s_waitcnt vmcnt(0)" ::: "memory");
    __builtin_amdgcn_s_barrier();
    const u16* Ah = AhB + buf * 16384;
    const u16* Bb = SMEM + 49152 + buf * 8192;
    const bool dost = (kt + 2 < KT);
    const int k2 = (kt + 2) << 6;
    u16* sA = SMEM + sbuf * 16384 + dOff;
    u16* sB = SMEM + 49152 + sbuf * 8192 + dOff;

    short8 af0[4], af1[4];
    // phase 0: stage A-h0(kt+2); read A frags + B nc0; 8 MFMA
    if (dost) STGU(aS0, sA, k2);
#pragma unroll
    for (int mr = 0; mr < 4; ++mr) {
      const u16* ar = Ah + (arow + mr * 16) * 64;
      af0[mr] = *(const short8*)(ar + (u ^ x7) * 8);
      af1[mr] = *(const short8*)(ar + ((4 + u) ^ x7) * 8);
    }
    PHASE(0)
    // phase 1: stage A-h1
    if (dost) STGU(aS1, sA + 8192, k2);
    PHASE(1)
    // phase 2: stage B
    if (dost) STGU(bS, sB, k2);
    PHASE(2)
    // phase 3
    PHASE(3)
    buf = (buf == 2) ? 0 : buf + 1;
    sbuf = (sbuf == 2) ? 0 : sbuf + 1;
  }
#undef PHASE
#undef STGU

  // ----------------------------- epilogues -----------------------------
  if (OUTBF16) {
    __syncthreads();
    const int rmode = (bcol < 1024) ? 0 : (bcol < 2048) ? 1 : 2;  // q / k / v
    if (rmode < 2) {
      const float sc = (rmode == 0) ? 0.18033688f : 1.0f;  // 0.125*log2(e)
#pragma unroll
      for (int mr = 0; mr < 4; ++mr)
#pragma unroll
        for (int rr = 0; rr < 4; ++rr) {
          const int row = wm * 64 + mr * 16 + u * 4 + rr;  // 0..255
          const int s = (brow + row) & 2047;
          const float2 c0 = cst[s * 32 + lr];
          const float2 c1 = cst[s * 32 + 16 + lr];
          const float x10 = acc[mr][0][rr], x11 = acc[mr][1][rr];
          const float x20 = acc[mr][2][rr], x21 = acc[mr][3][rr];
          u16* lp = SMEM + row * 136 + wn * 64 + lr;
          lp[0]  = f2bu((x10 * c0.x - x20 * c0.y) * sc);
          lp[16] = f2bu((x11 * c1.x - x21 * c1.y) * sc);
          lp[32] = f2bu((x10 * c0.y + x20 * c0.x) * sc);
          lp[48] = f2bu((x11 * c1.y + x21 * c1.x) * sc);
        }
      __syncthreads();
      u16* cp = (u16*)C;
#pragma unroll
      for (int i = 0; i < 8; ++i) {
        const int e = i * 4096 + tid * 8;
        const int row = e >> 7, col = e & 127;
        short8 v = *(const short8*)(SMEM + row * 136 + col);
        *(short8*)(cp + (size_t)(brow + row) * N + bcol + col) = v;
      }
    } else {
      // v third: transpose in LDS [128 d][264 pad] -> vt[(b*16+h)*64+d][s]
#pragma unroll
      for (int mr = 0; mr < 4; ++mr)
#pragma unroll
        for (int j2 = 0; j2 < 4; ++j2)
#pragma unroll
          for (int rr = 0; rr < 4; ++rr) {
            const int dl = wn * 64 + j2 * 16 + lr;          // 0..127
            const int sl = wm * 64 + mr * 16 + u * 4 + rr;  // 0..255
            SMEM[dl * 264 + sl] = f2bu(acc[mr][j2][rr]);
          }
      __syncthreads();
      const int bb2 = brow >> 11;
      const int sbase = brow & 2047;
#pragma unroll
      for (int i = 0; i < 8; ++i) {
        const int e = i * 4096 + tid * 8;
        const int dl = e >> 8, sl = e & 255;
        short8 v = *(const short8*)(SMEM + dl * 264 + sl);
        *(short8*)(vtp + (size_t)(bb2 * 1024 + (bcol - 2048) + dl) * 2048 + sbase + sl) = v;
      }
    }
  } else {
    // f32 out: two row-half passes through [128][132] f32 tile
    float* FS = (float*)SMEM;
#pragma unroll
    for (int hh = 0; hh < 2; ++hh) {
      __syncthreads();
      if ((wm >> 1) == hh) {
#pragma unroll
        for (int mr = 0; mr < 4; ++mr)
#pragma unroll
          for (int j2 = 0; j2 < 4; ++j2)
#pragma unroll
            for (int rr = 0; rr < 4; ++rr)
              FS[((wm & 1) * 64 + mr * 16 + u * 4 + rr) * 132 + wn * 64 + j2 * 16 + lr] =
                  acc[mr][j2][rr];
      }
      __syncthreads();
      float* cp = (float*)C;
#pragma unroll
      for (int i = 0; i < 8; ++i) {
        const int e = i * 2048 + tid * 4;
        const int row = e >> 7, col = e & 127;
        float4 v = *(const float4*)(FS + row * 132 + col);
        *(float4*)(cp + (size_t)(brow + hh * 128 + row) * N + bcol + col) = v;
      }
    }
  }
}

// ---------------- causal flash attention (R16-proven, 67.4 us) ----------------
__global__ __launch_bounds__(256, 4) void k_attn(const u16* __restrict__ qkv,
                                                 const u16* __restrict__ vt,
                                                 u16* __restrict__ obuf) {
  __shared__ __align__(16) u16 Ksm[2][64 * 64];
  __shared__ __align__(16) u16 Vsm[2][64 * 64];

  const int tid = threadIdx.x;
  const int wid = tid >> 6;
  const int lane = tid & 63;
  const int l31 = lane & 31;
  const int hi = lane >> 5;
  const int r7 = l31 & 7;

  const int fid = blockIdx.x;
  const int a = fid & 3, bq = (fid >> 8) & 3;
  const int bh = (fid >> 2) & 63;
  const int sel = a ^ bq;
  const int qt = (sel == 0) ? bq : (sel == 1) ? 7 - bq : (sel == 2) ? 8 + bq : 15 - bq;

  const int b = bh >> 4;
  const int h = bh & 15;

  const float NEG = -__builtin_inff();

  const int srow = lane >> 3;
  const int scol = ((lane & 7) ^ srow) * 8;
  const u16* ksrc0 = qkv + (size_t)(b * Ssz + wid * 16 + srow) * 3072 + 1024 + h * 64 + scol;
  const u16* ksrc1 = ksrc0 + (size_t)8 * 3072;
  const u16* vsrc0 = vt + ((size_t)bh * 64 + wid * 16 + srow) * Ssz + scol;
  const u16* vsrc1 = vsrc0 + (size_t)8 * Ssz;
  u16* kD0 = Ksm[0] + wid * 1024;
  u16* vD0 = Vsm[0] + wid * 1024;

  const int q0 = qt * 128;
  const int qrow = q0 + (wid << 5) + l31;

  const u16* qptr = qkv + (size_t)(b * Ssz + qrow) * 3072 + h * 64 + hi * 8;
  short8 qf[4];
#pragma unroll
  for (int s = 0; s < 4; ++s) qf[s] = *(const short8*)(qptr + s * 16);

  f32x16 o0 = {0.f}, o1 = {0.f};
  float lsum = 0.f;

  const int ntiles = 2 * qt + 2;
  const int lastT = 2 * qt + (wid >> 1);

  cp16(ksrc0, kD0);
  cp16(ksrc1, kD0 + 512);
  cp16(vsrc0, vD0);
  cp16(vsrc1, vD0 + 512);

  const u16* kS0 = ksrc0 + (size_t)64 * 3072;
  const u16* kS1 = ksrc1 + (size_t)64 * 3072;
  const u16* vS0 = vsrc0 + 64;
  const u16* vS1 = vsrc1 + 64;

  for (int t = 0; t < ntiles; ++t) {
    __syncthreads();
    if (t + 1 < ntiles) {
      const int nb = (t + 1) & 1;
      cp16(kS0, kD0 + nb * 4096);
      cp16(kS1, kD0 + nb * 4096 + 512);
      cp16(vS0, vD0 + nb * 4096);
      cp16(vS1, vD0 + nb * 4096 + 512);
      kS0 += (size_t)64 * 3072;
      kS1 += (size_t)64 * 3072;
      vS0 += 64;
      vS1 += 64;
    }
    if (t > lastT) continue;

    const u16* kbuf = Ksm[t & 1];
    const u16* vbuf = Vsm[t & 1];
    const int kv0 = t << 6;

    f32x16 st0 = {0.f}, st1 = {0.f};
    __builtin_amdgcn_s_setprio(1);
#pragma unroll
    for (int s = 0; s < 4; ++s) {
      const int slot = (((2 * s + hi) ^ r7) << 3);
      short8 k0 = *(const short8*)(kbuf + l31 * 64 + slot);
      short8 k1 = *(const short8*)(kbuf + (32 + l31) * 64 + slot);
      st0 = mfma3232(k0, qf[s], st0);
      st1 = mfma3232(k1, qf[s], st1);
    }
    __builtin_amdgcn_s_setprio(0);

    if (t == lastT) {
      const int kb0 = kv0 + 4 * hi;
#pragma unroll
      for (int r = 0; r < 16; ++r) {
        const int ko = (r & 3) + 8 * (r >> 2);
        if (kb0 + ko > qrow) st0[r] = NEG;
        if (kb0 + 32 + ko > qrow) st1[r] = NEG;
      }
    }

    float rsp[4] = {0.f, 0.f, 0.f, 0.f};
#pragma unroll
    for (int r = 0; r < 16; ++r) {
      const float p0 = ex2(st0[r]);
      const float p1 = ex2(st1[r]);
      st0[r] = p0;
      st1[r] = p1;
      rsp[r & 3] += p0 + p1;
    }
    lsum += (rsp[0] + rsp[1]) + (rsp[2] + rsp[3]);

    u32 wa[8], wb[8];
#pragma unroll
    for (int g = 0; g < 4; ++g) {
      wa[g] = pk2(st0[4 * g + 0], st0[4 * g + 1]);
      wb[g] = pk2(st0[4 * g + 2], st0[4 * g + 3]);
      wa[4 + g] = pk2(st1[4 * g + 0], st1[4 * g + 1]);
      wb[4 + g] = pk2(st1[4 * g + 2], st1[4 * g + 3]);
    }

#pragma unroll
    for (int s = 0; s < 4; ++s) {
      const u32 uA0 = wa[2 * s], uA1 = wa[2 * s + 1];
      const u32 uB0 = wb[2 * s], uB1 = wb[2 * s + 1];
      const u32 tA0 = __shfl_xor(uA0, 32), tA1 = __shfl_xor(uA1, 32);
      const u32 tB0 = __shfl_xor(uB0, 32), tB1 = __shfl_xor(uB1, 32);
      u32x4 pw;
      pw.x = hi ? tA1 : uA0;
      pw.y = hi ? tB1 : uB0;
      pw.z = hi ? uA1 : tA0;
      pw.w = hi ? uB1 : tB0;
      short8 pfrag = *(short8*)&pw;
      const int slot = (((2 * s + hi) ^ r7) << 3);
      short8 v0 = *(const short8*)(vbuf + l31 * 64 + slot);
      short8 v1 = *(const short8*)(vbuf + (32 + l31) * 64 + slot);
      __builtin_amdgcn_s_setprio(1);
      o0 = mfma3232(v0, pfrag, o0);
      o1 = mfma3232(v1, pfrag, o1);
      __builtin_amdgcn_s_setprio(0);
    }
  }

  const float lt = lsum + __shfl_xor(lsum, 32);
  const float inv = 1.0f / lt;
  u16* orow = obuf + (size_t)(b * Ssz + qrow) * 1024 + h * 64;
#pragma unroll
  for (int j = 0; j < 4; ++j) {
    ushort4 s0, s1;
    s0.x = f2bu(o0[4 * j + 0] * inv);
    s0.y = f2bu(o0[4 * j + 1] * inv);
    s0.z = f2bu(o0[4 * j + 2] * inv);
    s0.w = f2bu(o0[4 * j + 3] * inv);
    s1.x = f2bu(o1[4 * j + 0] * inv);
    s1.y = f2bu(o1[4 * j + 1] * inv);
    s1.z = f2bu(o1[4 * j + 2] * inv);
    s1.w = f2bu(o1[4 * j + 3] * inv);
    *(ushort4*)(orow + 8 * j + 4 * hi) = s0;
    *(ushort4*)(orow + 32 + 8 * j + 4 * hi) = s1;
  }
}

// ---------------- launcher ----------------
extern "C" void kernel_launch(void* const* d_in, const int* in_sizes, int n_in,
                              void* d_out, int out_size, void* d_ws, size_t ws_size,
                              hipStream_t stream) {
  const float* x = (const float*)d_in[0];
  const float* wqkv = (const float*)d_in[1];
  const float* wout = (const float*)d_in[2];

  char* ws = (char*)d_ws;
  u16* xb      = (u16*)(ws + 0);           // 8192*1024*2   = 16777216
  u16* wqkvb   = (u16*)(ws + 16777216);    // 3072*1024*2   = 6291456
  u16* woutb   = (u16*)(ws + 23068672);    // 1024*1024*2   = 2097152
  u16* qkv     = (u16*)(ws + 25165824);    // 8192*3072*2   = 50331648 (v third unused)
  u16* vt      = (u16*)(ws + 75497472);    // 64*64*2048*2  = 16777216
  u16* obuf    = (u16*)(ws + 92274688);    // 8192*1024*2   = 16777216
  float2* cst  = (float2*)(ws + 109051904);// 2048*32*8     = 524288 -> ~104.5 MB

  k_prep<<<2048, 256, 0, stream>>>(
      (const float4*)x, (ushort4*)xb, Mrows * Dsz / 4,
      (const float4*)wqkv, (ushort4*)wqkvb, 3 * Dsz * Dsz / 4,
      (const float4*)wout, (ushort4*)woutb, Dsz * Dsz / 4, cst);

  // qkv = x @ w_qkv^T with fused RoPE epilogue; v third -> vt transposed.
  // 768 blocks = 8 XCDs x 3 col-tiles x 32 row-tiles (exactly 3 blocks/CU).
  k_gemm2<true><<<768, 512, 0, stream>>>(xb, wqkvb, qkv, 3072, 1024, cst, 3, vt);

  // causal flash attention -> obuf [8192][1024] bf16
  k_attn<<<1024, 256, 0, stream>>>(qkv, vt, obuf);

  // out = obuf @ w_out^T (fp32) — 256 blocks = 8 x 1 x 32 (exactly 1/CU)
  k_gemm2<false><<<256, 512, 0, stream>>>(obuf, woutb, d_out, 1024, 1024, nullptr, 1, nullptr);
}

// Round 18
// 168.032 us; speedup vs baseline: 1.0180x; 1.0180x over previous
//
#include <hip/hip_runtime.h>
#include <hip/hip_bf16.h>

#define DEV static __device__ __forceinline__

typedef unsigned short u16;
typedef unsigned int u32;
typedef __attribute__((ext_vector_type(8))) short short8;
typedef __attribute__((ext_vector_type(4))) float f32x4;
typedef __attribute__((ext_vector_type(16))) float f32x16;
typedef __attribute__((ext_vector_type(4))) u32 u32x4;

static constexpr int Bsz = 4, Ssz = 2048, Dsz = 1024, Hn = 16, HD = 64;
static constexpr int Mrows = Bsz * Ssz;  // 8192

DEV u16 f2bu(float f) {
  union { float f; u32 u; } a; a.f = f;
  u32 u = a.u;
  u32 r = (u + 0x7FFFu + ((u >> 16) & 1u)) >> 16;
  return (u16)r;
}
DEV float b2f(u16 v) {
  union { u32 u; float f; } a; a.u = ((u32)v) << 16;
  return a.f;
}
DEV u32 pk2(float lo, float hi2) {  // packed bf16 pair (RNE), lo -> [15:0]
  __hip_bfloat162 t = __float22bfloat162_rn(make_float2(lo, hi2));
  u32 r; __builtin_memcpy(&r, &t, 4); return r;
}
DEV f32x16 mfma3232(short8 a, short8 b, f32x16 c) {
  return __builtin_amdgcn_mfma_f32_32x32x16_bf16(a, b, c, 0, 0, 0);
}
DEV float ex2(float x) { return __builtin_amdgcn_exp2f(x); }

// ------ prep: fp32->bf16 casts (x, w_qkv, w_out) + RoPE cos/sin table -------
__global__ void k_prep(const float4* __restrict__ s0, ushort4* __restrict__ d0, int n0,
                       const float4* __restrict__ s1, ushort4* __restrict__ d1, int n1,
                       const float4* __restrict__ s2, ushort4* __restrict__ d2, int n2,
                       float2* __restrict__ cst) {
  const int stride = gridDim.x * blockDim.x;
  const int ncast = n0 + n1 + n2;
  const int total = ncast + Ssz * 32;
  for (int i = blockIdx.x * blockDim.x + threadIdx.x; i < total; i += stride) {
    if (i < ncast) {
      const float4* s; ushort4* d; int k;
      if (i < n0) { s = s0; d = d0; k = i; }
      else if (i < n0 + n1) { s = s1; d = d1; k = i - n0; }
      else { s = s2; d = d2; k = i - n0 - n1; }
      float4 v = s[k];
      ushort4 o;
      o.x = f2bu(v.x); o.y = f2bu(v.y); o.z = f2bu(v.z); o.w = f2bu(v.w);
      d[k] = o;
    } else {
      const int k = i - ncast;
      const int s = k >> 5, dd = k & 31;
      const float inv = powf(10000.0f, -(float)dd / 32.0f);
      const float fr = (float)s * inv;
      cst[k] = make_float2(cosf(fr), sinf(fr));
    }
  }
}

// ---------------- GEMM: C[M][N] = A[M][K] * W[N][K]^T ----------------
// 2-phase 128x128 tile (R16-benched best): BK=64, 2 buffers, vmcnt(0)+s_barrier
// per step, oct^(row&7) LDS swizzle via pre-swizzled global_load_lds source.
// Epilogues LDS-coalesced (q/k RoPE-fused, v transposed into vt, f32 tile).
DEV void cp16(const u16* g, u16* l) {
  __builtin_amdgcn_global_load_lds((const __attribute__((address_space(1))) u32*)g,
                                   (__attribute__((address_space(3))) u32*)l, 16, 0, 0);
}

template <bool OUTBF16>
__global__ __launch_bounds__(256, 2) void k_gemm(const u16* __restrict__ A,
                                                 const u16* __restrict__ W,
                                                 void* __restrict__ C, int N, int K,
                                                 const float2* __restrict__ cst, int cpx,
                                                 u16* __restrict__ vtp) {
  __shared__ __align__(16) u16 SMEM[33792];  // 67.6 KB
  const int tid = threadIdx.x;
  const int wid = tid >> 6, lane = tid & 63;
  const int lr = lane & 15, u = lane >> 4;
  const int wm = wid >> 1, wn = wid & 1;

  const int wg = blockIdx.x;
  const int xcd = wg & 7;
  const int j = wg >> 3;
  const int brow = (j / cpx) * 128;
  const int bcol = (xcd * cpx + j % cpx) * 128;

  const int rw = wid * 32 + (lane >> 3);
  const int octS = ((lane & 7) ^ (rw & 7)) * 8;
  const u16* aS = A + (size_t)(brow + rw) * K + octS;
  const u16* bS = W + (size_t)(bcol + rw) * K + octS;
  const int dBase = wid * 2048 + lane * 8;

  const int aBase = (wm * 64 + lr) * 64;
  const int bBase = (wn * 64 + lr) * 64;
  const int o0 = (u ^ (lane & 7)) * 8;
  const int o1 = ((4 + u) ^ (lane & 7)) * 8;

  f32x4 acc[4][4];
#pragma unroll
  for (int i = 0; i < 4; ++i)
#pragma unroll
    for (int j2 = 0; j2 < 4; ++j2) acc[i][j2] = (f32x4){0.f, 0.f, 0.f, 0.f};

  const int nt = K >> 6;

#define STG(kk, bb)                                                    \
  do {                                                                 \
    u16* ad = SMEM + (bb)*8192 + dBase;                                \
    u16* bd = SMEM + 16384 + (bb)*8192 + dBase;                        \
    cp16(aS + (kk), ad);                                               \
    cp16(aS + (size_t)8 * K + (kk), ad + 512);                         \
    cp16(aS + (size_t)16 * K + (kk), ad + 1024);                       \
    cp16(aS + (size_t)24 * K + (kk), ad + 1536);                       \
    cp16(bS + (kk), bd);                                               \
    cp16(bS + (size_t)8 * K + (kk), bd + 512);                         \
    cp16(bS + (size_t)16 * K + (kk), bd + 1024);                       \
    cp16(bS + (size_t)24 * K + (kk), bd + 1536);                       \
  } while (0)

  STG(0, 0);

  for (int t = 0; t < nt; ++t) {
    asm volatile("s_waitcnt vmcnt(0)" ::: "memory");
    __builtin_amdgcn_s_barrier();
    if (t + 1 < nt) STG((t + 1) << 6, (t + 1) & 1);
    const u16* ab = SMEM + (t & 1) * 8192;
    const u16* bb = SMEM + 16384 + (t & 1) * 8192;
    short8 a0[4], a1[4], b0[4], b1[4];
#pragma unroll
    for (int mr = 0; mr < 4; ++mr) {
      a0[mr] = *(const short8*)(ab + aBase + mr * 1024 + o0);
      a1[mr] = *(const short8*)(ab + aBase + mr * 1024 + o1);
    }
#pragma unroll
    for (int nr = 0; nr < 4; ++nr) {
      b0[nr] = *(const short8*)(bb + bBase + nr * 1024 + o0);
      b1[nr] = *(const short8*)(bb + bBase + nr * 1024 + o1);
    }
    __builtin_amdgcn_s_setprio(1);
#pragma unroll
    for (int mr = 0; mr < 4; ++mr)
#pragma unroll
      for (int nr = 0; nr < 4; ++nr)
        acc[mr][nr] =
            __builtin_amdgcn_mfma_f32_16x16x32_bf16(a0[mr], b0[nr], acc[mr][nr], 0, 0, 0);
#pragma unroll
    for (int mr = 0; mr < 4; ++mr)
#pragma unroll
      for (int nr = 0; nr < 4; ++nr)
        acc[mr][nr] =
            __builtin_amdgcn_mfma_f32_16x16x32_bf16(a1[mr], b1[nr], acc[mr][nr], 0, 0, 0);
    __builtin_amdgcn_s_setprio(0);
  }
#undef STG

  if (OUTBF16) {
    __syncthreads();
    const int rmode = (bcol < 1024) ? 0 : (bcol < 2048) ? 1 : 2;  // q / k / v
    if (rmode < 2) {
      const float sc = (rmode == 0) ? 0.18033688f : 1.0f;  // 0.125*log2(e)
#pragma unroll
      for (int mr = 0; mr < 4; ++mr)
#pragma unroll
        for (int r = 0; r < 4; ++r) {
          const int row = wm * 64 + mr * 16 + u * 4 + r;
          const int s = (brow + row) & 2047;
          const float2 c0 = cst[s * 32 + lr];
          const float2 c1 = cst[s * 32 + 16 + lr];
          const float x10 = acc[mr][0][r], x11 = acc[mr][1][r];
          const float x20 = acc[mr][2][r], x21 = acc[mr][3][r];
          u16* lp = SMEM + row * 136 + wn * 64 + lr;
          lp[0]  = f2bu((x10 * c0.x - x20 * c0.y) * sc);
          lp[16] = f2bu((x11 * c1.x - x21 * c1.y) * sc);
          lp[32] = f2bu((x10 * c0.y + x20 * c0.x) * sc);
          lp[48] = f2bu((x11 * c1.y + x21 * c1.x) * sc);
        }
      __syncthreads();
      u16* cp = (u16*)C;
#pragma unroll
      for (int i = 0; i < 8; ++i) {
        const int e = i * 2048 + tid * 8;
        const int row = e >> 7, col = e & 127;
        short8 v = *(const short8*)(SMEM + row * 136 + col);
        *(short8*)(cp + (size_t)(brow + row) * N + bcol + col) = v;
      }
    } else {
#pragma unroll
      for (int mr = 0; mr < 4; ++mr)
#pragma unroll
        for (int nr = 0; nr < 4; ++nr)
#pragma unroll
          for (int r = 0; r < 4; ++r) {
            const int dl = wn * 64 + nr * 16 + lr;
            const int sl = wm * 64 + mr * 16 + u * 4 + r;
            SMEM[dl * 136 + sl] = f2bu(acc[mr][nr][r]);
          }
      __syncthreads();
      const int bb2 = brow >> 11;
      const int sbase = brow & 2047;
#pragma unroll
      for (int i = 0; i < 8; ++i) {
        const int e = i * 2048 + tid * 8;
        const int dl = e >> 7, sl = e & 127;
        const int gd = (bcol - 2048) + dl;
        short8 v = *(const short8*)(SMEM + dl * 136 + sl);
        *(short8*)(vtp + (size_t)(bb2 * 1024 + gd) * 2048 + sbase + sl) = v;
      }
    }
  } else {
    __syncthreads();
    float* FS = (float*)SMEM;
#pragma unroll
    for (int mr = 0; mr < 4; ++mr)
#pragma unroll
      for (int nr = 0; nr < 4; ++nr)
#pragma unroll
        for (int r = 0; r < 4; ++r)
          FS[(wm * 64 + mr * 16 + u * 4 + r) * 132 + wn * 64 + nr * 16 + lr] =
              acc[mr][nr][r];
    __syncthreads();
    float* cp = (float*)C;
#pragma unroll
    for (int i = 0; i < 16; ++i) {
      const int e = i * 1024 + tid * 4;
      const int row = e >> 7, col = e & 127;
      float4 v = *(const float4*)(FS + row * 132 + col);
      *(float4*)(cp + (size_t)(brow + row) * N + bcol + col) = v;
    }
  }
}

// ---------------- causal flash attention, 4-wave 32x32 swapped structure ------
// R16-benched best (67.4 us, VGPR 56, no spill). grid 1024 x 256 threads.
// Block = one 128-row q-supertile qt of head bh (dual-robust remap); wave w
// owns q rows [q0+32w,+32); lane owns ONE q-row. NO-MAX softmax (log2 domain,
// scale folded into Q): P = exp2(st) directly — exact under power-of-2 scaling.
// Per-tile lsum kept lane-partial; one cross-half shfl in the epilogue.
// K/V LDS [64][64] bf16 x 2 buffers, 16B-slot XOR swizzle, global_load_lds
// with pre-swizzled source.
// NOTE: permlane32_swap (R5) and KV-split variants (R12/R14/R15) failed on HW
// — do not reintroduce without isolated probes.
__global__ __launch_bounds__(256, 4) void k_attn(const u16* __restrict__ qkv,
                                                 const u16* __restrict__ vt,
                                                 u16* __restrict__ obuf) {
  __shared__ __align__(16) u16 Ksm[2][64 * 64];
  __shared__ __align__(16) u16 Vsm[2][64 * 64];

  const int tid = threadIdx.x;
  const int wid = tid >> 6;      // 0..3
  const int lane = tid & 63;
  const int l31 = lane & 31;
  const int hi = lane >> 5;
  const int r7 = l31 & 7;        // row&7 for swizzled ds_read

  // dual-robust (consecutive & stride-256) balanced qt remap
  const int fid = blockIdx.x;
  const int a = fid & 3, bq = (fid >> 8) & 3;
  const int bh = (fid >> 2) & 63;
  const int sel = a ^ bq;
  const int qt = (sel == 0) ? bq : (sel == 1) ? 7 - bq : (sel == 2) ? 8 + bq : 15 - bq;

  const int b = bh >> 4;
  const int h = bh & 15;

  const float NEG = -__builtin_inff();

  const int srow = lane >> 3;                 // 0..7
  const int scol = ((lane & 7) ^ srow) * 8;   // pre-swizzled source col (elems)
  const u16* ksrc0 = qkv + (size_t)(b * Ssz + wid * 16 + srow) * 3072 + 1024 + h * 64 + scol;
  const u16* ksrc1 = ksrc0 + (size_t)8 * 3072;
  const u16* vsrc0 = vt + ((size_t)bh * 64 + wid * 16 + srow) * Ssz + scol;
  const u16* vsrc1 = vsrc0 + (size_t)8 * Ssz;
  u16* kD0 = Ksm[0] + wid * 1024;
  u16* vD0 = Vsm[0] + wid * 1024;

  const int q0 = qt * 128;
  const int qrow = q0 + (wid << 5) + l31;

  const u16* qptr = qkv + (size_t)(b * Ssz + qrow) * 3072 + h * 64 + hi * 8;
  short8 qf[4];
#pragma unroll
  for (int s = 0; s < 4; ++s) qf[s] = *(const short8*)(qptr + s * 16);

  f32x16 o0 = {0.f}, o1 = {0.f};
  float lsum = 0.f;

  const int ntiles = 2 * qt + 2;
  const int lastT = 2 * qt + (wid >> 1);

  cp16(ksrc0, kD0);
  cp16(ksrc1, kD0 + 512);
  cp16(vsrc0, vD0);
  cp16(vsrc1, vD0 + 512);

  const u16* kS0 = ksrc0 + (size_t)64 * 3072;
  const u16* kS1 = ksrc1 + (size_t)64 * 3072;
  const u16* vS0 = vsrc0 + 64;
  const u16* vS1 = vsrc1 + 64;

  for (int t = 0; t < ntiles; ++t) {
    __syncthreads();
    if (t + 1 < ntiles) {
      const int nb = (t + 1) & 1;
      cp16(kS0, kD0 + nb * 4096);
      cp16(kS1, kD0 + nb * 4096 + 512);
      cp16(vS0, vD0 + nb * 4096);
      cp16(vS1, vD0 + nb * 4096 + 512);
      kS0 += (size_t)64 * 3072;
      kS1 += (size_t)64 * 3072;
      vS0 += 64;
      vS1 += 64;
    }
    if (t > lastT) continue;

    const u16* kbuf = Ksm[t & 1];
    const u16* vbuf = Vsm[t & 1];
    const int kv0 = t << 6;

    f32x16 st0 = {0.f}, st1 = {0.f};
    __builtin_amdgcn_s_setprio(1);
#pragma unroll
    for (int s = 0; s < 4; ++s) {
      const int slot = (((2 * s + hi) ^ r7) << 3);
      short8 k0 = *(const short8*)(kbuf + l31 * 64 + slot);
      short8 k1 = *(const short8*)(kbuf + (32 + l31) * 64 + slot);
      st0 = mfma3232(k0, qf[s], st0);
      st1 = mfma3232(k1, qf[s], st1);
    }
    __builtin_amdgcn_s_setprio(0);

    if (t == lastT) {
      const int kb0 = kv0 + 4 * hi;
#pragma unroll
      for (int r = 0; r < 16; ++r) {
        const int ko = (r & 3) + 8 * (r >> 2);
        if (kb0 + ko > qrow) st0[r] = NEG;
        if (kb0 + 32 + ko > qrow) st1[r] = NEG;
      }
    }

    float rsp[4] = {0.f, 0.f, 0.f, 0.f};
#pragma unroll
    for (int r = 0; r < 16; ++r) {
      const float p0 = ex2(st0[r]);
      const float p1 = ex2(st1[r]);
      st0[r] = p0;
      st1[r] = p1;
      rsp[r & 3] += p0 + p1;
    }
    lsum += (rsp[0] + rsp[1]) + (rsp[2] + rsp[3]);

    u32 wa[8], wb[8];
#pragma unroll
    for (int g = 0; g < 4; ++g) {
      wa[g] = pk2(st0[4 * g + 0], st0[4 * g + 1]);
      wb[g] = pk2(st0[4 * g + 2], st0[4 * g + 3]);
      wa[4 + g] = pk2(st1[4 * g + 0], st1[4 * g + 1]);
      wb[4 + g] = pk2(st1[4 * g + 2], st1[4 * g + 3]);
    }

#pragma unroll
    for (int s = 0; s < 4; ++s) {
      const u32 uA0 = wa[2 * s], uA1 = wa[2 * s + 1];
      const u32 uB0 = wb[2 * s], uB1 = wb[2 * s + 1];
      const u32 tA0 = __shfl_xor(uA0, 32), tA1 = __shfl_xor(uA1, 32);
      const u32 tB0 = __shfl_xor(uB0, 32), tB1 = __shfl_xor(uB1, 32);
      u32x4 pw;
      pw.x = hi ? tA1 : uA0;
      pw.y = hi ? tB1 : uB0;
      pw.z = hi ? uA1 : tA0;
      pw.w = hi ? uB1 : tB0;
      short8 pfrag = *(short8*)&pw;
      const int slot = (((2 * s + hi) ^ r7) << 3);
      short8 v0 = *(const short8*)(vbuf + l31 * 64 + slot);
      short8 v1 = *(const short8*)(vbuf + (32 + l31) * 64 + slot);
      __builtin_amdgcn_s_setprio(1);
      o0 = mfma3232(v0, pfrag, o0);
      o1 = mfma3232(v1, pfrag, o1);
      __builtin_amdgcn_s_setprio(0);
    }
  }

  const float lt = lsum + __shfl_xor(lsum, 32);
  const float inv = 1.0f / lt;
  u16* orow = obuf + (size_t)(b * Ssz + qrow) * 1024 + h * 64;
#pragma unroll
  for (int j = 0; j < 4; ++j) {
    ushort4 s0, s1;
    s0.x = f2bu(o0[4 * j + 0] * inv);
    s0.y = f2bu(o0[4 * j + 1] * inv);
    s0.z = f2bu(o0[4 * j + 2] * inv);
    s0.w = f2bu(o0[4 * j + 3] * inv);
    s1.x = f2bu(o1[4 * j + 0] * inv);
    s1.y = f2bu(o1[4 * j + 1] * inv);
    s1.z = f2bu(o1[4 * j + 2] * inv);
    s1.w = f2bu(o1[4 * j + 3] * inv);
    *(ushort4*)(orow + 8 * j + 4 * hi) = s0;
    *(ushort4*)(orow + 32 + 8 * j + 4 * hi) = s1;
  }
}

// ---------------- launcher ----------------
extern "C" void kernel_launch(void* const* d_in, const int* in_sizes, int n_in,
                              void* d_out, int out_size, void* d_ws, size_t ws_size,
                              hipStream_t stream) {
  const float* x = (const float*)d_in[0];
  const float* wqkv = (const float*)d_in[1];
  const float* wout = (const float*)d_in[2];

  char* ws = (char*)d_ws;
  u16* xb      = (u16*)(ws + 0);           // 8192*1024*2   = 16777216
  u16* wqkvb   = (u16*)(ws + 16777216);    // 3072*1024*2   = 6291456
  u16* woutb   = (u16*)(ws + 23068672);    // 1024*1024*2   = 2097152
  u16* qkv     = (u16*)(ws + 25165824);    // 8192*3072*2   = 50331648 (v third unused)
  u16* vt      = (u16*)(ws + 75497472);    // 64*64*2048*2  = 16777216
  u16* obuf    = (u16*)(ws + 92274688);    // 8192*1024*2   = 16777216
  float2* cst  = (float2*)(ws + 109051904);// 2048*32*8     = 524288 -> ~104.5 MB

  k_prep<<<2048, 256, 0, stream>>>(
      (const float4*)x, (ushort4*)xb, Mrows * Dsz / 4,
      (const float4*)wqkv, (ushort4*)wqkvb, 3 * Dsz * Dsz / 4,
      (const float4*)wout, (ushort4*)woutb, Dsz * Dsz / 4, cst);

  // qkv = x @ w_qkv^T with fused RoPE epilogue; v third written transposed
  // straight into vt. 1536 blocks = 8 XCDs x 3 x 64.
  k_gemm<true><<<1536, 256, 0, stream>>>(xb, wqkvb, qkv, 3072, 1024, cst, 3, vt);

  // causal flash attention -> obuf [8192][1024] bf16
  k_attn<<<1024, 256, 0, stream>>>(qkv, vt, obuf);

  // out = obuf @ w_out^T  (fp32 out) — 512 blocks = 8 x 1 x 64
  k_gemm<false><<<512, 256, 0, stream>>>(obuf, woutb, d_out, 1024, 1024, nullptr, 1, nullptr);
}